// Round 19
// baseline (340.672 us; speedup 1.0000x reference)
//
#include <hip/hip_runtime.h>
#include <math.h>

#define N_NODES 100000
#define N_EDGES 1600000
#define IN_DIM 500
#define HID 64
#define NCLS 16
#define KP 512     // padded K for layer-1 GEMM
#define NSTEPS 16  // KP/32
#define NBUK 391   // buckets of 256 dsts: bucket = dst >> 8
#define NPAD (NBUK * 256)
#define EPB 8192   // edges per bucket-phase block (512 threads)
#define CAP 8192   // fixed slots per bucket (mean 4096; ws is ~800MB)
#define BROW 520   // persistent A row pitch (ushorts), 16B-aligned

typedef __attribute__((ext_vector_type(8))) short short8;
typedef __attribute__((ext_vector_type(4))) float f32x4;

__device__ __forceinline__ unsigned short f2bf(float f) {
    unsigned u = __builtin_bit_cast(unsigned, f);
    return (unsigned short)((u + 0x7FFFu + ((u >> 16) & 1u)) >> 16);
}
__device__ __forceinline__ float bf2f(unsigned short s) {
    unsigned u = ((unsigned)s) << 16;
    return __builtin_bit_cast(float, u);
}
__device__ __forceinline__ unsigned pack2(unsigned short a, unsigned short b) {
    return (unsigned)a | ((unsigned)b << 16);
}
// async global->LDS, 16B per lane; LDS dest is wave-uniform base + lane*16
__device__ __forceinline__ void gload16(const void* g, void* l) {
    __builtin_amdgcn_global_load_lds(
        (const __attribute__((address_space(1))) unsigned*)g,
        (__attribute__((address_space(3))) unsigned*)l, 16, 0, 0);
}

// ---------------------------------------------------------------------------
// K0: build Bt[192][512] bf16 = transpose of {w1[0], w1[1], root1}, zero-pad K.
// ---------------------------------------------------------------------------
__global__ __launch_bounds__(256) void k0_bt(
    const float* __restrict__ w1, const float* __restrict__ root1,
    unsigned short* __restrict__ Bt)
{
    const int b = blockIdx.x;  // 0..191
    const float* src;
    int c;
    if (b < 64)        { src = w1;                c = b; }
    else if (b < 128)  { src = w1 + IN_DIM * HID; c = b - 64; }
    else               { src = root1;             c = b - 128; }
    for (int k = threadIdx.x; k < KP; k += 256) {
        float v = (k < IN_DIM) ? src[k * HID + c] : 0.f;
        Bt[b * KP + k] = f2bf(v);
    }
}

// ---------------------------------------------------------------------------
// CSR build with fixed-capacity bucket regions (R16, unchanged).
// ---------------------------------------------------------------------------
__global__ __launch_bounds__(512) void csr_bzero(int* __restrict__ bkcur)
{
    if (threadIdx.x < NBUK) bkcur[threadIdx.x] = threadIdx.x * CAP;
}

__global__ __launch_bounds__(512) void csr_bucket(
    const int* __restrict__ ei, const float* __restrict__ ea,
    int* __restrict__ bkcur, uint2* __restrict__ epk)
{
    __shared__ int hcnt[NBUK];
    __shared__ int hbase[NBUK];

    const int tid = threadIdx.x;
    const int start = blockIdx.x * EPB;
    const int eend = min(start + EPB, N_EDGES);

    for (int i = tid; i < NBUK; i += 512) hcnt[i] = 0;
    __syncthreads();

#pragma unroll
    for (int j = 0; j < EPB / 512; ++j) {
        const int e = start + j * 512 + tid;
        if (e < eend) atomicAdd(&hcnt[ei[N_EDGES + e] >> 8], 1);
    }
    __syncthreads();

    for (int b = tid; b < NBUK; b += 512) {
        const int c = hcnt[b];
        hbase[b] = c ? atomicAdd(&bkcur[b], c) : 0;
    }
    __syncthreads();
    for (int i = tid; i < NBUK; i += 512) hcnt[i] = 0;
    __syncthreads();

#pragma unroll
    for (int j = 0; j < EPB / 512; ++j) {
        const int e = start + j * 512 + tid;
        if (e < eend) {
            const int src = ei[e];
            const int dst = ei[N_EDGES + e];
            const float v = fminf(fmaxf(ea[e], 0.f), 1.f - 1e-6f);
            const unsigned vq = (unsigned)(v * 16777216.0f);  // 24-bit fixed
            const int bk = dst >> 8;
            const int r = atomicAdd(&hcnt[bk], 1);
            epk[hbase[bk] + r] =
                make_uint2((unsigned)src, ((unsigned)(dst & 255) << 24) | vq);
        }
    }
}

__global__ __launch_bounds__(256) void csr_place(
    const int* __restrict__ bkcur, const uint2* __restrict__ epk,
    uint2* __restrict__ epkS, int* __restrict__ off, int* __restrict__ deg)
{
    __shared__ int hist[256];
    __shared__ int sc[256];
    __shared__ int cur[256];

    const int b = blockIdx.x;
    const int tid = threadIdx.x;
    const int start = b * CAP;
    const int cnt = bkcur[b] - start;

    hist[tid] = 0;
    __syncthreads();
    for (int i = tid; i < cnt; i += 256)
        atomicAdd(&hist[epk[start + i].y >> 24], 1);
    __syncthreads();

    const int val = hist[tid];
    sc[tid] = val;
    for (int d = 1; d < 256; d <<= 1) {
        __syncthreads();
        int add = (tid >= d) ? sc[tid - d] : 0;
        __syncthreads();
        sc[tid] += add;
    }
    __syncthreads();
    const int mystart = start + sc[tid] - val;  // exclusive within bucket
    off[(b << 8) + tid] = mystart;
    deg[(b << 8) + tid] = val;
    cur[tid] = mystart;
    __syncthreads();

    for (int i = tid; i < cnt; i += 256) {
        const uint2 u = epk[start + i];
        const int dl = u.y >> 24;
        const float v = (float)(u.y & 0xFFFFFFu) * 5.9604644775390625e-8f;
        const int pos = atomicAdd(&cur[dl], 1);
        epkS[pos] = make_uint2(u.x, __builtin_bit_cast(unsigned, v));
    }
}

// ---------------------------------------------------------------------------
// K1: bf16 MFMA GEMM — A STAGED ONCE (full contiguous rows), B double-buffer
// staged per step (proven R11 pattern). Clean test of the DRAM-page theory:
// prior ~111us variants touched each 2KB x row 16x in 128B slices; here each
// row is read ONCE as a contiguous burst in phase 1 (fp32->bf16 into a
// persistent 66.6KB LDS strip). K-loop A-frags are ds_read_b128 (no per-step
// cvt VALU). Tile 64x192, 4 waves in 2x2.
// ---------------------------------------------------------------------------
union K1Smem {
    struct {
        unsigned short A[64 * BROW];  // 66,560 B persistent
        union {
            unsigned short B[2][192 * 32];  // 24,576 B
            unsigned short O[64 * 264];     // 33,792 B (epilogue)
        } u;
    } s;  // 100,352 B
};

__global__ __launch_bounds__(256) void k1_mfma(
    const float* __restrict__ x, const unsigned short* __restrict__ Bt,
    unsigned short* __restrict__ xw01, float* __restrict__ aggH)
{
    __shared__ K1Smem sm;

    const int tid = threadIdx.x;
    const int row0 = blockIdx.x * 64;
    const int w = tid >> 6;
    const int l = tid & 63;
    const int l16 = l & 15;
    const int koct = l >> 4;
    const int wr = w >> 1;
    const int wc = w & 1;

    // ---- phase 1: stage A once, full-row contiguous reads ----
    {
        unsigned short* myA = &sm.s.A[w * 16 * BROW];
        for (int rr = 0; rr < 16; ++rr) {
            int grow = row0 + w * 16 + rr;
            if (grow > N_NODES - 1) grow = N_NODES - 1;  // clamp; masked at store
            const float* xrow = x + (size_t)grow * IN_DIM;
            unsigned short* dst = &myA[rr * BROW];
            float4 v0 = *(const float4*)(xrow + l * 4);
            uint2 p0;
            p0.x = pack2(f2bf(v0.x), f2bf(v0.y));
            p0.y = pack2(f2bf(v0.z), f2bf(v0.w));
            *(uint2*)&dst[l * 4] = p0;
            float4 v1 = make_float4(0.f, 0.f, 0.f, 0.f);
            if (256 + l * 4 < IN_DIM) v1 = *(const float4*)(xrow + 256 + l * 4);
            uint2 p1;
            p1.x = pack2(f2bf(v1.x), f2bf(v1.y));
            p1.y = pack2(f2bf(v1.z), f2bf(v1.w));
            *(uint2*)&dst[256 + l * 4] = p1;
        }
    }

    // B staging addresses (R11 pattern): wave w stages cols (3w+i)*16+(l>>2).
    const unsigned short* bBase[3];
    int bLdsOff[3];
#pragma unroll
    for (int i = 0; i < 3; ++i) {
        const int coll = (3 * w + i) * 16 + (l >> 2);
        bBase[i] = Bt + (size_t)coll * KP + (l & 3) * 8;
        bLdsOff[i] = (3 * w + i) * 512;  // ushorts
    }
    auto ISSUE_B = [&](int s) {
        const int k0 = s * 32;
        const int buf = s & 1;
#pragma unroll
        for (int i = 0; i < 3; ++i)
            gload16(bBase[i] + k0, &sm.s.u.B[buf][bLdsOff[i]]);
    };

    ISSUE_B(0);
    __syncthreads();  // drains A ds_writes + B(0) gloads

    f32x4 acc[2][6];
#pragma unroll
    for (int i = 0; i < 2; ++i)
#pragma unroll
        for (int j = 0; j < 6; ++j) acc[i][j] = (f32x4){0.f, 0.f, 0.f, 0.f};

#pragma unroll
    for (int s = 0; s < NSTEPS; ++s) {
        if (s + 1 < NSTEPS) ISSUE_B(s + 1);  // opposite buffer; prior reads barrier-protected

        const int buf = s & 1;
        const unsigned short* LB = sm.s.u.B[buf];
        short8 af[2];
#pragma unroll
        for (int rb = 0; rb < 2; ++rb)
            af[rb] = *(const short8*)&sm.s.A[(wr * 32 + rb * 16 + l16) * BROW + s * 32 + koct * 8];
#pragma unroll
        for (int cf = 0; cf < 6; ++cf) {
            const int c = wc * 96 + cf * 16 + l16;
            short8 bfg = *(const short8*)&LB[c * 32 + koct * 8];
            acc[0][cf] = __builtin_amdgcn_mfma_f32_16x16x32_bf16(af[0], bfg, acc[0][cf], 0, 0, 0);
            acc[1][cf] = __builtin_amdgcn_mfma_f32_16x16x32_bf16(af[1], bfg, acc[1][cf], 0, 0, 0);
        }
        __syncthreads();  // B(s+1) landed; all reads of buf done before overwrite
    }

    // ---- epilogue (R16 pattern): O staging unions with B region ----
#pragma unroll
    for (int rb = 0; rb < 2; ++rb)
#pragma unroll
        for (int cf = 0; cf < 6; ++cf) {
            const int cg = wc * 96 + cf * 16 + l16;
            if (96 * wc + cf * 16 < 128) {  // wave-uniform: xw columns
#pragma unroll
                for (int reg = 0; reg < 4; ++reg) {
                    const int rloc = wr * 32 + rb * 16 + koct * 4 + reg;
                    const int idx = (cg < 64) ? (2 * cg) : (2 * cg - 127);
                    sm.s.u.O[rloc * 264 + idx] = f2bf(acc[rb][cf][reg]);
                }
            } else {  // aggH columns
#pragma unroll
                for (int reg = 0; reg < 4; ++reg) {
                    const int r = row0 + wr * 32 + rb * 16 + koct * 4 + reg;
                    if (r < N_NODES) aggH[(size_t)r * HID + (cg - 128)] = acc[rb][cf][reg];
                }
            }
        }
    __syncthreads();
    {
        const int row = tid >> 2, q = tid & 3;
        const int rg = row0 + row;
        if (rg < N_NODES) {
#pragma unroll
            for (int j = 0; j < 4; ++j) {
                uint4 v = *(const uint4*)&sm.s.u.O[row * 264 + q * 32 + j * 8];
                *(uint4*)&xw01[(size_t)rg * 128 + q * 32 + j * 8] = v;
            }
        }
    }
}

// ---------------------------------------------------------------------------
// AGG1: wave per node; lane = hidden dim. 8 edges in flight.
// ---------------------------------------------------------------------------
__global__ __launch_bounds__(256) void agg1(
    const int* __restrict__ off, const int* __restrict__ deg,
    const uint2* __restrict__ epk, const unsigned* __restrict__ xw01_u,
    float* __restrict__ aggH)
{
    const int n = blockIdx.x * 4 + (threadIdx.x >> 6);
    if (n >= N_NODES) return;
    const int d = threadIdx.x & 63;
    const int start = off[n];
    const int dg = deg[n];

    float acc = aggH[(size_t)n * HID + d];
    for (int i = 0; i < dg; i += 8) {
        unsigned srcs[8];
        float w0[8], w1[8];
#pragma unroll
        for (int j = 0; j < 8; ++j) {
            const bool ok = (i + j) < dg;
            const int idx = ok ? (start + i + j) : start;
            const uint2 t = epk[idx];
            const float v = __builtin_bit_cast(float, t.y);
            srcs[j] = t.x;
            w0[j] = ok ? (1.f - v) : 0.f;
            w1[j] = ok ? v : 0.f;
        }
        unsigned g[8];
#pragma unroll
        for (int j = 0; j < 8; ++j) g[j] = xw01_u[(size_t)srcs[j] * 64 + d];
#pragma unroll
        for (int j = 0; j < 8; ++j) {
            acc += w0[j] * bf2f((unsigned short)(g[j] & 0xFFFF));
            acc += w1[j] * bf2f((unsigned short)(g[j] >> 16));
        }
    }
    aggH[(size_t)n * HID + d] = acc;
}

// ---------------------------------------------------------------------------
// K3: h = relu(aggH + b1); hw01 = packed bf16 {h@w2[0], h@w2[1]}; agg2 = h@root2.
// ---------------------------------------------------------------------------
__global__ __launch_bounds__(256) void k3_relu_gemm(
    const float* __restrict__ aggH, const float* __restrict__ b1,
    const float* __restrict__ w2, const float* __restrict__ root2,
    unsigned* __restrict__ hw01_u, float* __restrict__ agg2)
{
    __shared__ float Ws[3 * HID * NCLS];
    __shared__ float Hs[16][HID];

    const int tid = threadIdx.x;
    for (int i = tid; i < 2 * HID * NCLS; i += 256) Ws[i] = w2[i];
    for (int i = tid; i < HID * NCLS; i += 256) Ws[2 * HID * NCLS + i] = root2[i];

    const int n0 = blockIdx.x * 16;
    for (int i = tid; i < 16 * HID; i += 256) {
        const int nl = i >> 6, k = i & 63;
        const float h = aggH[(size_t)(n0 + nl) * HID + k] + b1[k];
        Hs[nl][k] = fmaxf(h, 0.f);
    }
    __syncthreads();

    const int nl = tid >> 4;
    const int c = tid & 15;
    float a0 = 0.f, a1 = 0.f, a2 = 0.f;
#pragma unroll
    for (int k = 0; k < HID; ++k) {
        const float h = Hs[nl][k];
        a0 += h * Ws[0 * HID * NCLS + k * NCLS + c];
        a1 += h * Ws[1 * HID * NCLS + k * NCLS + c];
        a2 += h * Ws[2 * HID * NCLS + k * NCLS + c];
    }
    const size_t o = (size_t)(n0 + nl) * NCLS + c;
    hw01_u[o] = pack2(f2bf(a0), f2bf(a1));
    agg2[o] = a2;
}

// ---------------------------------------------------------------------------
// AGG2 + log_softmax fused: 16 lanes per node, 16 nodes per block.
// 8 edges in flight.
// ---------------------------------------------------------------------------
__global__ __launch_bounds__(256) void agg2_sm(
    const int* __restrict__ off, const int* __restrict__ deg,
    const uint2* __restrict__ epk, const unsigned* __restrict__ hw01_u,
    const float* __restrict__ agg2, const float* __restrict__ b2,
    float* __restrict__ out)
{
    const int n = blockIdx.x * 16 + (threadIdx.x >> 4);
    const int c = threadIdx.x & 15;
    const int start = off[n];
    const int dg = deg[n];

    float acc = agg2[(size_t)n * NCLS + c];
    for (int i = 0; i < dg; i += 8) {
        unsigned srcs[8];
        float w0[8], w1[8];
#pragma unroll
        for (int j = 0; j < 8; ++j) {
            const bool ok = (i + j) < dg;
            const int idx = ok ? (start + i + j) : start;
            const uint2 t = epk[idx];
            const float v = __builtin_bit_cast(float, t.y);
            srcs[j] = t.x;
            w0[j] = ok ? (1.f - v) : 0.f;
            w1[j] = ok ? v : 0.f;
        }
        unsigned g[8];
#pragma unroll
        for (int j = 0; j < 8; ++j) g[j] = hw01_u[(size_t)srcs[j] * NCLS + c];
#pragma unroll
        for (int j = 0; j < 8; ++j) {
            acc += w0[j] * bf2f((unsigned short)(g[j] & 0xFFFF));
            acc += w1[j] * bf2f((unsigned short)(g[j] >> 16));
        }
    }

    const float z = acc + b2[c];
    float m = z;
#pragma unroll
    for (int s = 1; s < 16; s <<= 1) m = fmaxf(m, __shfl_xor(m, s, 64));
    const float e = expf(z - m);
    float ssum = e;
#pragma unroll
    for (int s = 1; s < 16; s <<= 1) ssum += __shfl_xor(ssum, s, 64);
    out[(size_t)n * NCLS + c] = (z - m) - logf(ssum);
}

extern "C" void kernel_launch(void* const* d_in, const int* in_sizes, int n_in,
                              void* d_out, int out_size, void* d_ws, size_t ws_size,
                              hipStream_t stream) {
    const float* x = (const float*)d_in[0];
    const int* ei = (const int*)d_in[1];
    const float* ea = (const float*)d_in[2];
    const float* w1 = (const float*)d_in[3];
    const float* root1 = (const float*)d_in[4];
    const float* b1 = (const float*)d_in[5];
    const float* w2 = (const float*)d_in[6];
    const float* root2 = (const float*)d_in[7];
    const float* b2 = (const float*)d_in[8];
    float* out = (float*)d_out;

    char* ws = (char*)d_ws;
    unsigned short* xw01 = (unsigned short*)ws;                 // 25.6 MB
    float* aggH = (float*)(ws + 25600000);                      // 25.6 MB
    unsigned* hw01_u = (unsigned*)(ws + 51200000);              // 6.4 MB
    float* agg2 = (float*)(ws + 57600000);                      // 6.4 MB
    unsigned short* Bt = (unsigned short*)(ws + 64000000);      // 0.2 MB
    int* off = (int*)(ws + 64300000);                           // 0.4 MB (NPAD)
    int* deg = (int*)(ws + 64800000);                           // 0.4 MB (NPAD)
    int* bkcur = (int*)(ws + 65300000);                         // 1.6 KB
    uint2* epk = (uint2*)(ws + 65400000);                       // 25.6 MB (padded)
    uint2* epkS = (uint2*)(ws + 91100000);                      // 25.6 MB (padded)

    // CSR build (fixed-capacity bucket regions)
    csr_bzero<<<1, 512, 0, stream>>>(bkcur);
    csr_bucket<<<(N_EDGES + EPB - 1) / EPB, 512, 0, stream>>>(ei, ea, bkcur, epk);
    csr_place<<<NBUK, 256, 0, stream>>>(bkcur, epk, epkS, off, deg);

    // layer 1
    k0_bt<<<192, 256, 0, stream>>>(w1, root1, Bt);
    k1_mfma<<<(N_NODES + 63) / 64, 256, 0, stream>>>(x, Bt, xw01, aggH);
    agg1<<<(N_NODES + 3) / 4, 256, 0, stream>>>(off, deg, epkS, (const unsigned*)xw01, aggH);

    // layer 2
    k3_relu_gemm<<<N_NODES / 16, 256, 0, stream>>>(aggH, b1, w2, root2, hw01_u, agg2);
    agg2_sm<<<N_NODES / 16, 256, 0, stream>>>(off, deg, epkS, hw01_u, agg2, b2, out);
}

// Round 20
// 268.380 us; speedup vs baseline: 1.2694x; 1.2694x over previous
//
#include <hip/hip_runtime.h>
#include <math.h>

#define N_NODES 100000
#define N_EDGES 1600000
#define IN_DIM 500
#define HID 64
#define NCLS 16
#define KP 512     // padded K for layer-1 GEMM
#define NSTEPS 16  // KP/32
#define NBUK 391   // buckets of 256 dsts: bucket = dst >> 8
#define NPAD (NBUK * 256)
#define EPB_B 4096 // edges per bucket block (256 threads)
#define NBB ((N_EDGES + EPB_B - 1) / EPB_B)  // 391 bucket blocks
#define CAP 8192   // fixed slots per bucket (mean 4096; ws is ~800MB)

typedef __attribute__((ext_vector_type(8))) short short8;
typedef __attribute__((ext_vector_type(4))) float f32x4;

__device__ __forceinline__ unsigned short f2bf(float f) {
    unsigned u = __builtin_bit_cast(unsigned, f);
    return (unsigned short)((u + 0x7FFFu + ((u >> 16) & 1u)) >> 16);
}
__device__ __forceinline__ float bf2f(unsigned short s) {
    unsigned u = ((unsigned)s) << 16;
    return __builtin_bit_cast(float, u);
}
__device__ __forceinline__ unsigned pack2(unsigned short a, unsigned short b) {
    return (unsigned)a | ((unsigned)b << 16);
}
// async global->LDS, 16B per lane; LDS dest is wave-uniform base + lane*16
__device__ __forceinline__ void gload16(const void* g, void* l) {
    __builtin_amdgcn_global_load_lds(
        (const __attribute__((address_space(1))) unsigned*)g,
        (__attribute__((address_space(3))) unsigned*)l, 16, 0, 0);
}

// ---------------------------------------------------------------------------
// K0: build Bt[192][512] bf16 = transpose of {w1[0], w1[1], root1}, zero-pad
// K. Block 192 additionally initializes the bucket cursors (merged csr_bzero).
// ---------------------------------------------------------------------------
__global__ __launch_bounds__(256) void k0_bt(
    const float* __restrict__ w1, const float* __restrict__ root1,
    unsigned short* __restrict__ Bt, int* __restrict__ bkcur)
{
    const int b = blockIdx.x;  // 0..192
    if (b == 192) {
        for (int i = threadIdx.x; i < NBUK; i += 256) bkcur[i] = i * CAP;
        return;
    }
    const float* src;
    int c;
    if (b < 64)        { src = w1;                c = b; }
    else if (b < 128)  { src = w1 + IN_DIM * HID; c = b - 64; }
    else               { src = root1;             c = b - 128; }
    for (int k = threadIdx.x; k < KP; k += 256) {
        float v = (k < IN_DIM) ? src[k * HID + c] : 0.f;
        Bt[b * KP + k] = f2bf(v);
    }
}

// ---------------------------------------------------------------------------
// FAT kernel: blocks [0, NBB) run the bucket-scatter body; blocks
// [NBB, NBB+ceil(N/64)) run the proven R16 k1 MFMA body. The two are data-
// independent and have complementary resource profiles (latency-bound scalar
// scatter vs latency-bound MFMA staging) -> co-residency overlaps them.
// ---------------------------------------------------------------------------
union K1Smem {
    struct { float A[4][64 * 32]; unsigned short B[4][192 * 32]; } s;  // 80KB
    unsigned short O[64 * 264];       // k1 epilogue staging (33.8 KB)
    struct { int hcnt[NBUK]; int hbase[NBUK]; } bk;  // bucket body (3.1 KB)
};

__global__ __launch_bounds__(256) void fat_bucket_k1(
    const int* __restrict__ ei, const float* __restrict__ ea,
    int* __restrict__ bkcur, uint2* __restrict__ epk,
    const float* __restrict__ x, const unsigned short* __restrict__ Bt,
    unsigned short* __restrict__ xw01, float* __restrict__ aggH)
{
    __shared__ K1Smem sm;
    const int tid = threadIdx.x;

    if (blockIdx.x < NBB) {
        // ================= bucket-scatter body =================
        const int start = blockIdx.x * EPB_B;
        const int eend = min(start + EPB_B, N_EDGES);

        for (int i = tid; i < NBUK; i += 256) sm.bk.hcnt[i] = 0;
        __syncthreads();

#pragma unroll
        for (int j = 0; j < EPB_B / 256; ++j) {
            const int e = start + j * 256 + tid;
            if (e < eend) atomicAdd(&sm.bk.hcnt[ei[N_EDGES + e] >> 8], 1);
        }
        __syncthreads();

        for (int b = tid; b < NBUK; b += 256) {
            const int c = sm.bk.hcnt[b];
            sm.bk.hbase[b] = c ? atomicAdd(&bkcur[b], c) : 0;
        }
        __syncthreads();
        for (int i = tid; i < NBUK; i += 256) sm.bk.hcnt[i] = 0;
        __syncthreads();

#pragma unroll
        for (int j = 0; j < EPB_B / 256; ++j) {
            const int e = start + j * 256 + tid;
            if (e < eend) {
                const int src = ei[e];
                const int dst = ei[N_EDGES + e];
                const float v = fminf(fmaxf(ea[e], 0.f), 1.f - 1e-6f);
                const unsigned vq = (unsigned)(v * 16777216.0f);  // 24-bit fixed
                const int bk = dst >> 8;
                const int r = atomicAdd(&sm.bk.hcnt[bk], 1);
                epk[sm.bk.hbase[bk] + r] =
                    make_uint2((unsigned)src, ((unsigned)(dst & 255) << 24) | vq);
            }
        }
        return;
    }

    // ================= k1 MFMA body (R16-proven, verbatim) =================
    const int row0 = (blockIdx.x - NBB) * 64;
    const int w = tid >> 6;
    const int l = tid & 63;
    const int l16 = l & 15;
    const int koct = l >> 4;
    const int wr = w >> 1;
    const int wc = w & 1;

    f32x4 acc[2][6];
#pragma unroll
    for (int i = 0; i < 2; ++i)
#pragma unroll
        for (int j = 0; j < 6; ++j) acc[i][j] = (f32x4){0.f, 0.f, 0.f, 0.f};

    const int aChunk4 = (l & 7) * 4;
    const float* aBase[2];
    int aLdsOff[2];
#pragma unroll
    for (int i = 0; i < 2; ++i) {
        const int rowl = (2 * w + i) * 8 + (l >> 3);
        int grow = row0 + rowl;
        if (grow > N_NODES - 1) grow = N_NODES - 1;
        aBase[i] = x + (size_t)grow * IN_DIM;
        aLdsOff[i] = (2 * w + i) * 256;  // floats
    }
    const unsigned short* bBase[3];
    int bLdsOff[3];
#pragma unroll
    for (int i = 0; i < 3; ++i) {
        const int coll = (3 * w + i) * 16 + (l >> 2);
        bBase[i] = Bt + (size_t)coll * KP + (l & 3) * 8;
        bLdsOff[i] = (3 * w + i) * 512;  // ushorts
    }

    auto ISSUE = [&](int s) {
        const int k0 = s * 32;
        const int buf = s & 3;
#pragma unroll
        for (int i = 0; i < 2; ++i) {
            int gk = k0 + aChunk4; if (gk > IN_DIM - 4) gk = IN_DIM - 4;
            gload16(aBase[i] + gk, &sm.s.A[buf][aLdsOff[i]]);
        }
#pragma unroll
        for (int i = 0; i < 3; ++i)
            gload16(bBase[i] + k0, &sm.s.B[buf][bLdsOff[i]]);
    };

    ISSUE(0);
    ISSUE(1);
    ISSUE(2);

#pragma unroll
    for (int s = 0; s < NSTEPS; ++s) {
        if (s < NSTEPS - 2)       asm volatile("s_waitcnt vmcnt(10)" ::: "memory");
        else if (s == NSTEPS - 2) asm volatile("s_waitcnt vmcnt(5)" ::: "memory");
        else                      asm volatile("s_waitcnt vmcnt(0)" ::: "memory");
        __builtin_amdgcn_s_barrier();
        asm volatile("" ::: "memory");
        if (s + 3 < NSTEPS) ISSUE(s + 3);

        const int buf = s & 3;
        const float* LA = sm.s.A[buf];
        const unsigned short* LB = sm.s.B[buf];
        short8 af[2];
#pragma unroll
        for (int rb = 0; rb < 2; ++rb) {
            const int r = wr * 32 + rb * 16 + l16;
            f32x4 f0 = *(const f32x4*)&LA[r * 32 + koct * 8];
            f32x4 f1 = *(const f32x4*)&LA[r * 32 + koct * 8 + 4];
            short8 a;
            a[0] = (short)f2bf(f0[0]); a[1] = (short)f2bf(f0[1]);
            a[2] = (short)f2bf(f0[2]); a[3] = (short)f2bf(f0[3]);
            a[4] = (short)f2bf(f1[0]); a[5] = (short)f2bf(f1[1]);
            a[6] = (short)f2bf(f1[2]); a[7] = (short)f2bf(f1[3]);
            af[rb] = a;
        }
#pragma unroll
        for (int cf = 0; cf < 6; ++cf) {
            const int c = wc * 96 + cf * 16 + l16;
            short8 bfg = *(const short8*)&LB[c * 32 + koct * 8];
            acc[0][cf] = __builtin_amdgcn_mfma_f32_16x16x32_bf16(af[0], bfg, acc[0][cf], 0, 0, 0);
            acc[1][cf] = __builtin_amdgcn_mfma_f32_16x16x32_bf16(af[1], bfg, acc[1][cf], 0, 0, 0);
        }
    }
    __syncthreads();

#pragma unroll
    for (int rb = 0; rb < 2; ++rb)
#pragma unroll
        for (int cf = 0; cf < 6; ++cf) {
            const int cg = wc * 96 + cf * 16 + l16;
            if (96 * wc + cf * 16 < 128) {
#pragma unroll
                for (int reg = 0; reg < 4; ++reg) {
                    const int rloc = wr * 32 + rb * 16 + koct * 4 + reg;
                    const int idx = (cg < 64) ? (2 * cg) : (2 * cg - 127);
                    sm.O[rloc * 264 + idx] = f2bf(acc[rb][cf][reg]);
                }
            } else {
#pragma unroll
                for (int reg = 0; reg < 4; ++reg) {
                    const int r = row0 + wr * 32 + rb * 16 + koct * 4 + reg;
                    if (r < N_NODES) aggH[(size_t)r * HID + (cg - 128)] = acc[rb][cf][reg];
                }
            }
        }
    __syncthreads();
    {
        const int row = tid >> 2, q = tid & 3;
        const int rg = row0 + row;
        if (rg < N_NODES) {
#pragma unroll
            for (int j = 0; j < 4; ++j) {
                uint4 v = *(const uint4*)&sm.O[row * 264 + q * 32 + j * 8];
                *(uint4*)&xw01[(size_t)rg * 128 + q * 32 + j * 8] = v;
            }
        }
    }
}

// ---------------------------------------------------------------------------
// csr_place: per bucket, 2-pass (R16, unchanged).
// ---------------------------------------------------------------------------
__global__ __launch_bounds__(256) void csr_place(
    const int* __restrict__ bkcur, const uint2* __restrict__ epk,
    uint2* __restrict__ epkS, int* __restrict__ off, int* __restrict__ deg)
{
    __shared__ int hist[256];
    __shared__ int sc[256];
    __shared__ int cur[256];

    const int b = blockIdx.x;
    const int tid = threadIdx.x;
    const int start = b * CAP;
    const int cnt = bkcur[b] - start;

    hist[tid] = 0;
    __syncthreads();
    for (int i = tid; i < cnt; i += 256)
        atomicAdd(&hist[epk[start + i].y >> 24], 1);
    __syncthreads();

    const int val = hist[tid];
    sc[tid] = val;
    for (int d = 1; d < 256; d <<= 1) {
        __syncthreads();
        int add = (tid >= d) ? sc[tid - d] : 0;
        __syncthreads();
        sc[tid] += add;
    }
    __syncthreads();
    const int mystart = start + sc[tid] - val;  // exclusive within bucket
    off[(b << 8) + tid] = mystart;
    deg[(b << 8) + tid] = val;
    cur[tid] = mystart;
    __syncthreads();

    for (int i = tid; i < cnt; i += 256) {
        const uint2 u = epk[start + i];
        const int dl = u.y >> 24;
        const float v = (float)(u.y & 0xFFFFFFu) * 5.9604644775390625e-8f;
        const int pos = atomicAdd(&cur[dl], 1);
        epkS[pos] = make_uint2(u.x, __builtin_bit_cast(unsigned, v));
    }
}

// ---------------------------------------------------------------------------
// AGG1: wave per node; lane = hidden dim. 8 edges in flight.
// ---------------------------------------------------------------------------
__global__ __launch_bounds__(256) void agg1(
    const int* __restrict__ off, const int* __restrict__ deg,
    const uint2* __restrict__ epk, const unsigned* __restrict__ xw01_u,
    float* __restrict__ aggH)
{
    const int n = blockIdx.x * 4 + (threadIdx.x >> 6);
    if (n >= N_NODES) return;
    const int d = threadIdx.x & 63;
    const int start = off[n];
    const int dg = deg[n];

    float acc = aggH[(size_t)n * HID + d];
    for (int i = 0; i < dg; i += 8) {
        unsigned srcs[8];
        float w0[8], w1[8];
#pragma unroll
        for (int j = 0; j < 8; ++j) {
            const bool ok = (i + j) < dg;
            const int idx = ok ? (start + i + j) : start;
            const uint2 t = epk[idx];
            const float v = __builtin_bit_cast(float, t.y);
            srcs[j] = t.x;
            w0[j] = ok ? (1.f - v) : 0.f;
            w1[j] = ok ? v : 0.f;
        }
        unsigned g[8];
#pragma unroll
        for (int j = 0; j < 8; ++j) g[j] = xw01_u[(size_t)srcs[j] * 64 + d];
#pragma unroll
        for (int j = 0; j < 8; ++j) {
            acc += w0[j] * bf2f((unsigned short)(g[j] & 0xFFFF));
            acc += w1[j] * bf2f((unsigned short)(g[j] >> 16));
        }
    }
    aggH[(size_t)n * HID + d] = acc;
}

// ---------------------------------------------------------------------------
// K3: h = relu(aggH + b1); hw01 = packed bf16 {h@w2[0], h@w2[1]}; agg2 = h@root2.
// ---------------------------------------------------------------------------
__global__ __launch_bounds__(256) void k3_relu_gemm(
    const float* __restrict__ aggH, const float* __restrict__ b1,
    const float* __restrict__ w2, const float* __restrict__ root2,
    unsigned* __restrict__ hw01_u, float* __restrict__ agg2)
{
    __shared__ float Ws[3 * HID * NCLS];
    __shared__ float Hs[16][HID];

    const int tid = threadIdx.x;
    for (int i = tid; i < 2 * HID * NCLS; i += 256) Ws[i] = w2[i];
    for (int i = tid; i < HID * NCLS; i += 256) Ws[2 * HID * NCLS + i] = root2[i];

    const int n0 = blockIdx.x * 16;
    for (int i = tid; i < 16 * HID; i += 256) {
        const int nl = i >> 6, k = i & 63;
        const float h = aggH[(size_t)(n0 + nl) * HID + k] + b1[k];
        Hs[nl][k] = fmaxf(h, 0.f);
    }
    __syncthreads();

    const int nl = tid >> 4;
    const int c = tid & 15;
    float a0 = 0.f, a1 = 0.f, a2 = 0.f;
#pragma unroll
    for (int k = 0; k < HID; ++k) {
        const float h = Hs[nl][k];
        a0 += h * Ws[0 * HID * NCLS + k * NCLS + c];
        a1 += h * Ws[1 * HID * NCLS + k * NCLS + c];
        a2 += h * Ws[2 * HID * NCLS + k * NCLS + c];
    }
    const size_t o = (size_t)(n0 + nl) * NCLS + c;
    hw01_u[o] = pack2(f2bf(a0), f2bf(a1));
    agg2[o] = a2;
}

// ---------------------------------------------------------------------------
// AGG2 + log_softmax fused: 16 lanes per node, 16 nodes per block.
// 8 edges in flight.
// ---------------------------------------------------------------------------
__global__ __launch_bounds__(256) void agg2_sm(
    const int* __restrict__ off, const int* __restrict__ deg,
    const uint2* __restrict__ epk, const unsigned* __restrict__ hw01_u,
    const float* __restrict__ agg2, const float* __restrict__ b2,
    float* __restrict__ out)
{
    const int n = blockIdx.x * 16 + (threadIdx.x >> 4);
    const int c = threadIdx.x & 15;
    const int start = off[n];
    const int dg = deg[n];

    float acc = agg2[(size_t)n * NCLS + c];
    for (int i = 0; i < dg; i += 8) {
        unsigned srcs[8];
        float w0[8], w1[8];
#pragma unroll
        for (int j = 0; j < 8; ++j) {
            const bool ok = (i + j) < dg;
            const int idx = ok ? (start + i + j) : start;
            const uint2 t = epk[idx];
            const float v = __builtin_bit_cast(float, t.y);
            srcs[j] = t.x;
            w0[j] = ok ? (1.f - v) : 0.f;
            w1[j] = ok ? v : 0.f;
        }
        unsigned g[8];
#pragma unroll
        for (int j = 0; j < 8; ++j) g[j] = hw01_u[(size_t)srcs[j] * NCLS + c];
#pragma unroll
        for (int j = 0; j < 8; ++j) {
            acc += w0[j] * bf2f((unsigned short)(g[j] & 0xFFFF));
            acc += w1[j] * bf2f((unsigned short)(g[j] >> 16));
        }
    }

    const float z = acc + b2[c];
    float m = z;
#pragma unroll
    for (int s = 1; s < 16; s <<= 1) m = fmaxf(m, __shfl_xor(m, s, 64));
    const float e = expf(z - m);
    float ssum = e;
#pragma unroll
    for (int s = 1; s < 16; s <<= 1) ssum += __shfl_xor(ssum, s, 64);
    out[(size_t)n * NCLS + c] = (z - m) - logf(ssum);
}

extern "C" void kernel_launch(void* const* d_in, const int* in_sizes, int n_in,
                              void* d_out, int out_size, void* d_ws, size_t ws_size,
                              hipStream_t stream) {
    const float* x = (const float*)d_in[0];
    const int* ei = (const int*)d_in[1];
    const float* ea = (const float*)d_in[2];
    const float* w1 = (const float*)d_in[3];
    const float* root1 = (const float*)d_in[4];
    const float* b1 = (const float*)d_in[5];
    const float* w2 = (const float*)d_in[6];
    const float* root2 = (const float*)d_in[7];
    const float* b2 = (const float*)d_in[8];
    float* out = (float*)d_out;

    char* ws = (char*)d_ws;
    unsigned short* xw01 = (unsigned short*)ws;                 // 25.6 MB
    float* aggH = (float*)(ws + 25600000);                      // 25.6 MB
    unsigned* hw01_u = (unsigned*)(ws + 51200000);              // 6.4 MB
    float* agg2 = (float*)(ws + 57600000);                      // 6.4 MB
    unsigned short* Bt = (unsigned short*)(ws + 64000000);      // 0.2 MB
    int* off = (int*)(ws + 64300000);                           // 0.4 MB (NPAD)
    int* deg = (int*)(ws + 64800000);                           // 0.4 MB (NPAD)
    int* bkcur = (int*)(ws + 65300000);                         // 1.6 KB
    uint2* epk = (uint2*)(ws + 65400000);                       // 25.6 MB (padded)
    uint2* epkS = (uint2*)(ws + 91100000);                      // 25.6 MB (padded)

    // k0 (builds Bt + inits bucket cursors)
    k0_bt<<<193, 256, 0, stream>>>(w1, root1, Bt, bkcur);

    // FAT: bucket scatter (391 blocks) || k1 MFMA (1563 blocks) — independent
    fat_bucket_k1<<<NBB + (N_NODES + 63) / 64, 256, 0, stream>>>(
        ei, ea, bkcur, epk, x, Bt, xw01, aggH);

    // place -> layer-1 aggregate -> layer-2 transform -> layer-2 agg+softmax
    csr_place<<<NBUK, 256, 0, stream>>>(bkcur, epk, epkS, off, deg);
    agg1<<<(N_NODES + 3) / 4, 256, 0, stream>>>(off, deg, epkS, (const unsigned*)xw01, aggH);
    k3_relu_gemm<<<N_NODES / 16, 256, 0, stream>>>(aggH, b1, w2, root2, hw01_u, agg2);
    agg2_sm<<<N_NODES / 16, 256, 0, stream>>>(off, deg, epkS, hw01_u, agg2, b2, out);
}